// Round 2
// baseline (433.986 us; speedup 1.0000x reference)
//
#include <hip/hip_runtime.h>

// ---------------------------------------------------------------------------
// SwinV2 WindowAttention fused pipeline (bf16 MFMA, fp32 accumulate)
//   Bw=256 windows, N=144 tokens, C=512, H=16 heads, hd=32, nW=64
// Pipeline: cvt(x,Wqkv,Wproj,mask) -> cpb-mlp -> bias gather(bf16) ->
//           GEMM qkv (bf16 out, q pre-scaled) -> attn (bias+mask in acc-init)
//           -> GEMM proj (f32 out)
// ---------------------------------------------------------------------------

using f32x4  = __attribute__((ext_vector_type(4))) float;
using bf16x8 = __attribute__((ext_vector_type(8))) short;

__device__ __forceinline__ unsigned short f2bf(float f) {
  unsigned u = __float_as_uint(f);
  u = (u + 0x7fffu + ((u >> 16) & 1u)) >> 16;   // RNE
  return (unsigned short)u;
}
__device__ __forceinline__ float bf2f(unsigned short s) {
  return __uint_as_float(((unsigned)s) << 16);
}

typedef __attribute__((address_space(1))) unsigned int as1_u32;
typedef __attribute__((address_space(3))) unsigned int as3_u32;

__device__ __forceinline__ void gll16(const void* g, void* l) {
  // async global->LDS, 16B per lane; LDS dest must be wave-uniform base.
  __builtin_amdgcn_global_load_lds((const as1_u32*)g, (as3_u32*)l, 16, 0, 0);
}

// --------------------------- fp32 -> bf16 convert ---------------------------
__global__ void cvt_f32_bf16(const float4* __restrict__ in,
                             unsigned short* __restrict__ out, int n4) {
  int i = blockIdx.x * blockDim.x + threadIdx.x;
  int stride = gridDim.x * blockDim.x;
  for (; i < n4; i += stride) {
    float4 v = in[i];
    ushort4 o;
    o.x = f2bf(v.x); o.y = f2bf(v.y); o.z = f2bf(v.z); o.w = f2bf(v.w);
    *(ushort4*)(out + (size_t)i * 4) = o;
  }
}

// --------------------------- CPB MLP: tbl(529,16) ---------------------------
__global__ void cpb_mlp(const float* __restrict__ tbl_in,  // (529,2)
                        const float* __restrict__ w1,      // (512,2)
                        const float* __restrict__ b1,      // (512)
                        const float* __restrict__ w2,      // (16,512)
                        float* __restrict__ tbl_out) {     // (529,16)
  __shared__ float hid[512];
  const int p = blockIdx.x;
  const int t = threadIdx.x;
  float t0 = tbl_in[p * 2 + 0], t1 = tbl_in[p * 2 + 1];
  float hv = fmaf(w1[t * 2 + 0], t0, fmaf(w1[t * 2 + 1], t1, b1[t]));
  hid[t] = fmaxf(hv, 0.f);
  __syncthreads();
  const int head = t >> 5, j = t & 31;
  float partial = 0.f;
  for (int i = j; i < 512; i += 32) partial += hid[i] * w2[head * 512 + i];
#pragma unroll
  for (int mk = 16; mk >= 1; mk >>= 1) partial += __shfl_xor(partial, mk, 32);
  if (j == 0) tbl_out[p * 16 + head] = partial;
}

// ---------------- gather: bias_bf[h][n][m] (16,144,144) bf16 ----------------
__global__ void bias_gather(const float* __restrict__ tbl,          // (529,16)
                            const int* __restrict__ idx,            // (144,144)
                            unsigned short* __restrict__ bias_bf) { // (16,20736)
  int f = blockIdx.x * 256 + threadIdx.x;
  if (f >= 16 * 20736) return;
  int h = f / 20736;
  int p = f - h * 20736;
  bias_bf[f] = f2bf(tbl[idx[p] * 16 + h]);
}

// --------------------------- bf16 GEMM, C = A * B^T -------------------------
// A: [M][K] bf16 row-major, B: [N][K] bf16 row-major, K multiple of 32.
// 128x128 tile, 4 waves each owning 4x4 16x16 sub-tiles. m97 structure.
// QSCALE: multiply output cols < 512 by hd^-0.5 (folds attn scale into q).
template <bool OUT_BF16, bool QSCALE>
__global__ __launch_bounds__(256) void gemm_bt_k(
    const unsigned short* __restrict__ A, const unsigned short* __restrict__ B,
    const float* __restrict__ bias, void* __restrict__ C, int N, int K) {
  __shared__ __align__(16) unsigned short As[128 * 32];
  __shared__ __align__(16) unsigned short Bs[128 * 32];
  const int tid = threadIdx.x;
  const int wave = tid >> 6, lane = tid & 63;
  const int m0 = blockIdx.y << 7, n0 = blockIdx.x << 7;
  const int wr = wave >> 1, wc = wave & 1;
  const int l15 = lane & 15, l4 = lane >> 4;

  f32x4 acc[4][4] = {};

  const unsigned short* gA = A + (size_t)(m0 + wave * 32 + (lane >> 2)) * K + (lane & 3) * 8;
  const unsigned short* gB = B + (size_t)(n0 + wave * 32 + (lane >> 2)) * K + (lane & 3) * 8;
  unsigned short* lA = As + wave * 32 * 32;  // wave-uniform LDS base
  unsigned short* lB = Bs + wave * 32 * 32;

  for (int k0 = 0; k0 < K; k0 += 32) {
    __syncthreads();
    gll16(gA + k0, lA);
    gll16(gA + k0 + (size_t)16 * K, lA + 16 * 32);
    gll16(gB + k0, lB);
    gll16(gB + k0 + (size_t)16 * K, lB + 16 * 32);
    __syncthreads();
    bf16x8 af[4], bfr[4];
#pragma unroll
    for (int t = 0; t < 4; ++t) {
      af[t]  = *(const bf16x8*)(As + (wr * 64 + t * 16 + l15) * 32 + l4 * 8);
      bfr[t] = *(const bf16x8*)(Bs + (wc * 64 + t * 16 + l15) * 32 + l4 * 8);
    }
#pragma unroll
    for (int i = 0; i < 4; ++i)
#pragma unroll
      for (int j = 0; j < 4; ++j)
        acc[i][j] = __builtin_amdgcn_mfma_f32_16x16x32_bf16(af[i], bfr[j], acc[i][j], 0, 0, 0);
  }

#pragma unroll
  for (int i = 0; i < 4; ++i) {
    int rowb = m0 + wr * 64 + i * 16 + l4 * 4;
#pragma unroll
    for (int j = 0; j < 4; ++j) {
      int col = n0 + wc * 64 + j * 16 + l15;
      float bv = bias[col];
#pragma unroll
      for (int r = 0; r < 4; ++r) {
        size_t off = (size_t)(rowb + r) * N + col;
        float v = acc[i][j][r] + bv;
        if (QSCALE && col < 512) v *= 0.17677669529663688f;  // hd^-0.5
        if (OUT_BF16) ((unsigned short*)C)[off] = f2bf(v);
        else          ((float*)C)[off] = v;
      }
    }
  }
}

// ------------------------------- attention ----------------------------------
// One block (256 thr, 4 waves) per (b, h). qkv: [36864][1536] bf16
// (cols 0-511 = q (pre-scaled), 512-1023 = k, 1024-1535 = v at h*32+d).
// mask+bias are folded into the S-tile MFMA accumulator init (bf16 tables).
// LDS: SP[144][152] (scores->P), Vt[32][152] (V^T). 53,504 B -> 3 blocks/CU.
__global__ __launch_bounds__(256) void attn_k(
    const unsigned short* __restrict__ qkv,
    const unsigned short* __restrict__ maskbf,   // (64,144,144) bf16
    const unsigned short* __restrict__ biasbf,   // (16,144,144) bf16
    unsigned short* __restrict__ aout) {
  __shared__ __align__(16) unsigned short SP[144 * 152];
  __shared__ __align__(16) unsigned short Vt[32 * 152];

  const int h = blockIdx.x, b = blockIdx.y;
  const int tid = threadIdx.x;
  const int wave = tid >> 6, lane = tid & 63;
  const int l15 = lane & 15, l4 = lane >> 4;
  const size_t base = (size_t)b * 144 * 1536;

  // ---- stage V transposed (vectorized reads; scalar LDS scatter)
  for (int c = tid; c < 576; c += 256) {
    int n = c >> 2, p = c & 3;
    uint4 v = *(const uint4*)(qkv + base + (size_t)n * 1536 + 1024 + h * 32 + p * 8);
    unsigned short tmp[8];
    *(uint4*)tmp = v;
#pragma unroll
    for (int j = 0; j < 8; ++j) Vt[(p * 8 + j) * 152 + n] = tmp[j];
  }

  // ---- S = q K^T + mask + bias -> SP bf16. 81 tiles, acc init = mask+bias.
  const unsigned short* mrow = maskbf + (size_t)(b & 63) * 20736;
  const unsigned short* brow = biasbf + (size_t)h * 20736;
  for (int tt = wave; tt < 81; tt += 4) {
    int ti = tt / 9, tj = tt - ti * 9;
    bf16x8 aq = *(const bf16x8*)(qkv + base + (size_t)(ti * 16 + l15) * 1536 + h * 32 + l4 * 8);
    bf16x8 bk = *(const bf16x8*)(qkv + base + (size_t)(tj * 16 + l15) * 1536 + 512 + h * 32 + l4 * 8);
    f32x4 c;
#pragma unroll
    for (int r = 0; r < 4; ++r) {
      int rr = ti * 16 + l4 * 4 + r, cc = tj * 16 + l15;
      c[r] = bf2f(mrow[rr * 144 + cc]) + bf2f(brow[rr * 144 + cc]);
    }
    c = __builtin_amdgcn_mfma_f32_16x16x32_bf16(aq, bk, c, 0, 0, 0);
#pragma unroll
    for (int r = 0; r < 4; ++r)
      SP[(ti * 16 + l4 * 4 + r) * 152 + tj * 16 + l15] = f2bf(c[r]);
  }
  __syncthreads();

  // ---- softmax in-place: 16 groups x 16 lanes; group g rows g, g+16, ...
  {
    const int g = tid >> 4, j = tid & 15;
#pragma unroll
    for (int rr = 0; rr < 9; ++rr) {
      int r = g + rr * 16;
      float lv[9];
      float mx = -3.0e38f;
#pragma unroll
      for (int c2 = 0; c2 < 9; ++c2) {
        lv[c2] = bf2f(SP[r * 152 + j + c2 * 16]);
        mx = fmaxf(mx, lv[c2]);
      }
#pragma unroll
      for (int mk = 8; mk >= 1; mk >>= 1) mx = fmaxf(mx, __shfl_xor(mx, mk, 16));
      float sum = 0.f;
#pragma unroll
      for (int c2 = 0; c2 < 9; ++c2) {
        lv[c2] = __expf(lv[c2] - mx);
        sum += lv[c2];
      }
#pragma unroll
      for (int mk = 8; mk >= 1; mk >>= 1) sum += __shfl_xor(sum, mk, 16);
      float inv = 1.f / sum;
#pragma unroll
      for (int c2 = 0; c2 < 9; ++c2)
        SP[r * 152 + j + c2 * 16] = f2bf(lv[c2] * inv);
    }
  }
  __syncthreads();

  // ---- O = P V : 18 tiles (9 n-blocks x 2 d-blocks), exact K=144
  //      (4 full x32 steps + one x32 step with upper-half-zero fragments).
  for (int tt = wave; tt < 18; tt += 4) {
    int ti = tt >> 1, dj = tt & 1;
    f32x4 c = {0.f, 0.f, 0.f, 0.f};
    const unsigned short* pa = SP + (ti * 16 + l15) * 152;
    const unsigned short* vb = Vt + (dj * 16 + l15) * 152;
#pragma unroll
    for (int ks = 0; ks < 4; ++ks) {
      bf16x8 ap = *(const bf16x8*)(pa + ks * 32 + l4 * 8);
      bf16x8 bv = *(const bf16x8*)(vb + ks * 32 + l4 * 8);
      c = __builtin_amdgcn_mfma_f32_16x16x32_bf16(ap, bv, c, 0, 0, 0);
    }
    {
      bf16x8 ap = {}, bv = {};
      if (l4 < 2) {
        ap = *(const bf16x8*)(pa + 128 + l4 * 8);
        bv = *(const bf16x8*)(vb + 128 + l4 * 8);
      }
      c = __builtin_amdgcn_mfma_f32_16x16x32_bf16(ap, bv, c, 0, 0, 0);
    }
#pragma unroll
    for (int r = 0; r < 4; ++r) {
      int n = ti * 16 + l4 * 4 + r;
      int d = dj * 16 + l15;
      aout[((size_t)(b * 144 + n)) * 512 + h * 32 + d] = f2bf(c[r]);
    }
  }
}

// ------------------------------- launcher -----------------------------------
extern "C" void kernel_launch(void* const* d_in, const int* in_sizes, int n_in,
                              void* d_out, int out_size, void* d_ws, size_t ws_size,
                              hipStream_t stream) {
  const float* x        = (const float*)d_in[0];   // (256,144,512)
  const float* mask     = (const float*)d_in[1];   // (64,144,144)
  const float* qkv_w    = (const float*)d_in[2];   // (1536,512)
  const float* qkv_b    = (const float*)d_in[3];   // (1536)
  const float* proj_w   = (const float*)d_in[4];   // (512,512)
  const float* proj_b   = (const float*)d_in[5];   // (512)
  const float* cpb_w1   = (const float*)d_in[6];   // (512,2)
  const float* cpb_b1   = (const float*)d_in[7];   // (512)
  const float* cpb_w2   = (const float*)d_in[8];   // (16,512)
  const float* rel_tab  = (const float*)d_in[9];   // (1,23,23,2) = 529x2
  const int*   rel_idx  = (const int*)d_in[10];    // (144,144)
  float* out = (float*)d_out;

  char* ws = (char*)d_ws;
  unsigned short* x_bf    = (unsigned short*)(ws);                 // 37,748,736 B
  unsigned short* wq_bf   = (unsigned short*)(ws + 37748736);      //  1,572,864 B
  unsigned short* wp_bf   = (unsigned short*)(ws + 39321600);      //    524,288 B
  unsigned short* qkv_ws  = (unsigned short*)(ws + 39845888);      // 113,246,208 B
  unsigned short* attn_ws = (unsigned short*)(ws + 153092096);     // 37,748,736 B
  float*          tbl_ws  = (float*)(ws + 190840832);              //     33,856 B
  unsigned short* maskbf  = (unsigned short*)(ws + 190874688);     //  2,654,208 B
  unsigned short* biasbf  = (unsigned short*)(ws + 193528896);     //    663,552 B
  // total 194,192,448 B

  // fp32 -> bf16 conversions
  cvt_f32_bf16<<<2048, 256, 0, stream>>>((const float4*)x, x_bf, 4718592);
  cvt_f32_bf16<<<768, 256, 0, stream>>>((const float4*)qkv_w, wq_bf, 196608);
  cvt_f32_bf16<<<256, 256, 0, stream>>>((const float4*)proj_w, wp_bf, 65536);
  cvt_f32_bf16<<<1296, 256, 0, stream>>>((const float4*)mask, maskbf, 331776);

  // CPB bias (bf16 table)
  cpb_mlp<<<529, 512, 0, stream>>>(rel_tab, cpb_w1, cpb_b1, cpb_w2, tbl_ws);
  bias_gather<<<1296, 256, 0, stream>>>(tbl_ws, rel_idx, biasbf);

  // QKV GEMM: (36864,512) x (1536,512)^T -> bf16 (36864,1536), q cols scaled
  gemm_bt_k<true, true><<<dim3(12, 288), 256, 0, stream>>>(
      x_bf, wq_bf, qkv_b, (void*)qkv_ws, 1536, 512);

  // attention: one block per (head, window-batch)
  attn_k<<<dim3(16, 256), 256, 0, stream>>>(qkv_ws, maskbf, biasbf, attn_ws);

  // proj GEMM: (36864,512) x (512,512)^T -> f32 out
  gemm_bt_k<false, false><<<dim3(4, 288), 256, 0, stream>>>(
      attn_ws, wp_bf, proj_b, (void*)out, 512, 512);
}

// Round 3
// 407.615 us; speedup vs baseline: 1.0647x; 1.0647x over previous
//
#include <hip/hip_runtime.h>

// ---------------------------------------------------------------------------
// SwinV2 WindowAttention fused pipeline (bf16 MFMA, fp32 accumulate)
//   Bw=256 windows, N=144 tokens, C=512, H=16 heads, hd=32, nW=64
// Pipeline: cvt(x,Wqkv,Wproj,mask) -> cpb-mlp -> bias gather(bf16) ->
//           GEMM qkv (bf16 out, q pre-scaled) -> attn (swapped-QK^T,
//           in-register softmax) -> GEMM proj (f32 out)
// ---------------------------------------------------------------------------

using f32x4  = __attribute__((ext_vector_type(4))) float;
using bf16x8 = __attribute__((ext_vector_type(8))) short;

__device__ __forceinline__ unsigned short f2bf(float f) {
  unsigned u = __float_as_uint(f);
  u = (u + 0x7fffu + ((u >> 16) & 1u)) >> 16;   // RNE
  return (unsigned short)u;
}
__device__ __forceinline__ float bf2f(unsigned short s) {
  return __uint_as_float(((unsigned)s) << 16);
}

typedef __attribute__((address_space(1))) unsigned int as1_u32;
typedef __attribute__((address_space(3))) unsigned int as3_u32;

__device__ __forceinline__ void gll16(const void* g, void* l) {
  // async global->LDS, 16B per lane; LDS dest must be wave-uniform base.
  __builtin_amdgcn_global_load_lds((const as1_u32*)g, (as3_u32*)l, 16, 0, 0);
}

// --------------------------- fp32 -> bf16 convert ---------------------------
__global__ void cvt_f32_bf16(const float4* __restrict__ in,
                             unsigned short* __restrict__ out, int n4) {
  int i = blockIdx.x * blockDim.x + threadIdx.x;
  int stride = gridDim.x * blockDim.x;
  for (; i < n4; i += stride) {
    float4 v = in[i];
    ushort4 o;
    o.x = f2bf(v.x); o.y = f2bf(v.y); o.z = f2bf(v.z); o.w = f2bf(v.w);
    *(ushort4*)(out + (size_t)i * 4) = o;
  }
}

// --------------------------- CPB MLP: tbl(529,16) ---------------------------
__global__ void cpb_mlp(const float* __restrict__ tbl_in,  // (529,2)
                        const float* __restrict__ w1,      // (512,2)
                        const float* __restrict__ b1,      // (512)
                        const float* __restrict__ w2,      // (16,512)
                        float* __restrict__ tbl_out) {     // (529,16)
  __shared__ float hid[512];
  const int p = blockIdx.x;
  const int t = threadIdx.x;
  float t0 = tbl_in[p * 2 + 0], t1 = tbl_in[p * 2 + 1];
  float hv = fmaf(w1[t * 2 + 0], t0, fmaf(w1[t * 2 + 1], t1, b1[t]));
  hid[t] = fmaxf(hv, 0.f);
  __syncthreads();
  const int head = t >> 5, j = t & 31;
  float partial = 0.f;
  for (int i = j; i < 512; i += 32) partial += hid[i] * w2[head * 512 + i];
#pragma unroll
  for (int mk = 16; mk >= 1; mk >>= 1) partial += __shfl_xor(partial, mk, 32);
  if (j == 0) tbl_out[p * 16 + head] = partial;
}

// ---------------- gather: bias_bf[h][n][m] (16,144,144) bf16 ----------------
__global__ void bias_gather(const float* __restrict__ tbl,          // (529,16)
                            const int* __restrict__ idx,            // (144,144)
                            unsigned short* __restrict__ bias_bf) { // (16,20736)
  int f = blockIdx.x * 256 + threadIdx.x;
  if (f >= 16 * 20736) return;
  int h = f / 20736;
  int p = f - h * 20736;
  bias_bf[f] = f2bf(tbl[idx[p] * 16 + h]);
}

// --------------------------- bf16 GEMM, C = A * B^T -------------------------
// A: [M][K] bf16 row-major, B: [N][K] bf16 row-major, K multiple of 32.
// 128x128 tile, 4 waves each owning 4x4 16x16 sub-tiles. m97 structure.
// QSCALE: multiply output cols < 512 by hd^-0.5 (folds attn scale into q).
template <bool OUT_BF16, bool QSCALE>
__global__ __launch_bounds__(256) void gemm_bt_k(
    const unsigned short* __restrict__ A, const unsigned short* __restrict__ B,
    const float* __restrict__ bias, void* __restrict__ C, int N, int K) {
  __shared__ __align__(16) unsigned short As[128 * 32];
  __shared__ __align__(16) unsigned short Bs[128 * 32];
  const int tid = threadIdx.x;
  const int wave = tid >> 6, lane = tid & 63;
  const int m0 = blockIdx.y << 7, n0 = blockIdx.x << 7;
  const int wr = wave >> 1, wc = wave & 1;
  const int l15 = lane & 15, l4 = lane >> 4;

  f32x4 acc[4][4] = {};

  const unsigned short* gA = A + (size_t)(m0 + wave * 32 + (lane >> 2)) * K + (lane & 3) * 8;
  const unsigned short* gB = B + (size_t)(n0 + wave * 32 + (lane >> 2)) * K + (lane & 3) * 8;
  unsigned short* lA = As + wave * 32 * 32;  // wave-uniform LDS base
  unsigned short* lB = Bs + wave * 32 * 32;

  for (int k0 = 0; k0 < K; k0 += 32) {
    __syncthreads();
    gll16(gA + k0, lA);
    gll16(gA + k0 + (size_t)16 * K, lA + 16 * 32);
    gll16(gB + k0, lB);
    gll16(gB + k0 + (size_t)16 * K, lB + 16 * 32);
    __syncthreads();
    bf16x8 af[4], bfr[4];
#pragma unroll
    for (int t = 0; t < 4; ++t) {
      af[t]  = *(const bf16x8*)(As + (wr * 64 + t * 16 + l15) * 32 + l4 * 8);
      bfr[t] = *(const bf16x8*)(Bs + (wc * 64 + t * 16 + l15) * 32 + l4 * 8);
    }
#pragma unroll
    for (int i = 0; i < 4; ++i)
#pragma unroll
      for (int j = 0; j < 4; ++j)
        acc[i][j] = __builtin_amdgcn_mfma_f32_16x16x32_bf16(af[i], bfr[j], acc[i][j], 0, 0, 0);
  }

#pragma unroll
  for (int i = 0; i < 4; ++i) {
    int rowb = m0 + wr * 64 + i * 16 + l4 * 4;
#pragma unroll
    for (int j = 0; j < 4; ++j) {
      int col = n0 + wc * 64 + j * 16 + l15;
      float bv = bias[col];
#pragma unroll
      for (int r = 0; r < 4; ++r) {
        size_t off = (size_t)(rowb + r) * N + col;
        float v = acc[i][j][r] + bv;
        if (QSCALE && col < 512) v *= 0.17677669529663688f;  // hd^-0.5
        if (OUT_BF16) ((unsigned short*)C)[off] = f2bf(v);
        else          ((float*)C)[off] = v;
      }
    }
  }
}

// ------------------------------- attention ----------------------------------
// One block (256 thr, 4 waves) per (b, h). qkv: [36864][1536] bf16
// (cols 0-511 = q (pre-scaled), 512-1023 = k, 1024-1535 = v at h*32+d).
// Swapped QK^T: per row-tile rt the wave computes S^T tiles mfma(K,Q) so each
// lane holds row n = rt*16+l15, keys m = kt*16+l4*4+r -> softmax fully
// in-register (2 shfl_xor over lanes 16/32). P -> LDS via b64 writes, PV reads
// b128 fragments. mask+bias folded via 8B vector loads into the acc init.
// LDS: P[144][152] + Vt[32][152] = 53,504 B -> 3 blocks/CU.
__global__ __launch_bounds__(256) void attn_k(
    const unsigned short* __restrict__ qkv,
    const unsigned short* __restrict__ maskbf,   // (64,144,144) bf16
    const unsigned short* __restrict__ biasbf,   // (16,144,144) bf16
    unsigned short* __restrict__ aout) {
  __shared__ __align__(16) unsigned short P[144 * 152];
  __shared__ __align__(16) unsigned short Vt[32 * 152];

  const int h = blockIdx.x, b = blockIdx.y;
  const int tid = threadIdx.x;
  const int wave = tid >> 6, lane = tid & 63;
  const int l15 = lane & 15, l4 = lane >> 4;
  const size_t base = (size_t)b * 144 * 1536;

  // ---- stage V transposed. chunk = dblk*144 + m so consecutive lanes hit
  //      consecutive m -> Vt write banks spread (2-way max, free).
  for (int c = tid; c < 576; c += 256) {
    int dblk = c / 144;
    int m = c - dblk * 144;
    uint4 v = *(const uint4*)(qkv + base + (size_t)m * 1536 + 1024 + h * 32 + dblk * 8);
    unsigned short tmp[8];
    *(uint4*)tmp = v;
#pragma unroll
    for (int j = 0; j < 8; ++j) Vt[(dblk * 8 + j) * 152 + m] = tmp[j];
  }

  // ---- S^T + in-register softmax + P write, per row-tile
  const unsigned short* mrow = maskbf + (size_t)(b & 63) * 20736;
  const unsigned short* brow = biasbf + (size_t)h * 20736;
  for (int rt = wave; rt < 9; rt += 4) {
    const int n = rt * 16 + l15;
    // B-frag: Q[n][k=l4*8+j] (q pre-scaled by hd^-0.5 in GEMM epilogue)
    bf16x8 qf = *(const bf16x8*)(qkv + base + (size_t)n * 1536 + h * 32 + l4 * 8);
    f32x4 acc[9];
#pragma unroll
    for (int kt = 0; kt < 9; ++kt) {
      // A-frag: K[m=kt*16+l15][k=l4*8+j]
      bf16x8 kf = *(const bf16x8*)(qkv + base + (size_t)(kt * 16 + l15) * 1536 + 512 + h * 32 + l4 * 8);
      const int mq = kt * 16 + l4 * 4;   // lane's 4 consecutive m values
      ushort4 mv = *(const ushort4*)(mrow + n * 144 + mq);
      ushort4 bv = *(const ushort4*)(brow + n * 144 + mq);
      f32x4 ci;
      ci[0] = bf2f(mv.x) + bf2f(bv.x);
      ci[1] = bf2f(mv.y) + bf2f(bv.y);
      ci[2] = bf2f(mv.z) + bf2f(bv.z);
      ci[3] = bf2f(mv.w) + bf2f(bv.w);
      // D = K * Q^T = S^T: lane holds S[n][kt*16 + l4*4 + r]
      acc[kt] = __builtin_amdgcn_mfma_f32_16x16x32_bf16(kf, qf, ci, 0, 0, 0);
    }
    // softmax over the 144 keys of row n: 36 in-lane + 4 lanes (l4 = bits 4,5)
    float mx = -3.0e38f;
#pragma unroll
    for (int kt = 0; kt < 9; ++kt)
#pragma unroll
      for (int r = 0; r < 4; ++r) mx = fmaxf(mx, acc[kt][r]);
    mx = fmaxf(mx, __shfl_xor(mx, 16));
    mx = fmaxf(mx, __shfl_xor(mx, 32));
    float sum = 0.f;
#pragma unroll
    for (int kt = 0; kt < 9; ++kt)
#pragma unroll
      for (int r = 0; r < 4; ++r) {
        float p = __expf(acc[kt][r] - mx);
        acc[kt][r] = p;
        sum += p;
      }
    sum += __shfl_xor(sum, 16);
    sum += __shfl_xor(sum, 32);
    float inv = 1.0f / sum;
    unsigned short* prow = P + n * 152;
#pragma unroll
    for (int kt = 0; kt < 9; ++kt) {
      ushort4 o;
      o.x = f2bf(acc[kt][0] * inv);
      o.y = f2bf(acc[kt][1] * inv);
      o.z = f2bf(acc[kt][2] * inv);
      o.w = f2bf(acc[kt][3] * inv);
      *(ushort4*)(prow + kt * 16 + l4 * 4) = o;   // b64 write, 2-way banks
    }
  }
  __syncthreads();

  // ---- O = P V : 18 tiles (9 row-tiles x 2 d-tiles), exact K=144
  for (int tt = wave; tt < 18; tt += 4) {
    int rt = tt >> 1, dj = tt & 1;
    f32x4 c = {0.f, 0.f, 0.f, 0.f};
    const unsigned short* pa = P + (rt * 16 + l15) * 152;
    const unsigned short* vb = Vt + (dj * 16 + l15) * 152;
#pragma unroll
    for (int ks = 0; ks < 4; ++ks) {
      bf16x8 ap = *(const bf16x8*)(pa + ks * 32 + l4 * 8);
      bf16x8 bv = *(const bf16x8*)(vb + ks * 32 + l4 * 8);
      c = __builtin_amdgcn_mfma_f32_16x16x32_bf16(ap, bv, c, 0, 0, 0);
    }
    {
      bf16x8 ap = {}, bv = {};
      if (l4 < 2) {
        ap = *(const bf16x8*)(pa + 128 + l4 * 8);
        bv = *(const bf16x8*)(vb + 128 + l4 * 8);
      }
      c = __builtin_amdgcn_mfma_f32_16x16x32_bf16(ap, bv, c, 0, 0, 0);
    }
#pragma unroll
    for (int r = 0; r < 4; ++r) {
      int n = rt * 16 + l4 * 4 + r;
      int d = dj * 16 + l15;
      aout[((size_t)(b * 144 + n)) * 512 + h * 32 + d] = f2bf(c[r]);
    }
  }
}

// ------------------------------- launcher -----------------------------------
extern "C" void kernel_launch(void* const* d_in, const int* in_sizes, int n_in,
                              void* d_out, int out_size, void* d_ws, size_t ws_size,
                              hipStream_t stream) {
  const float* x        = (const float*)d_in[0];   // (256,144,512)
  const float* mask     = (const float*)d_in[1];   // (64,144,144)
  const float* qkv_w    = (const float*)d_in[2];   // (1536,512)
  const float* qkv_b    = (const float*)d_in[3];   // (1536)
  const float* proj_w   = (const float*)d_in[4];   // (512,512)
  const float* proj_b   = (const float*)d_in[5];   // (512)
  const float* cpb_w1   = (const float*)d_in[6];   // (512,2)
  const float* cpb_b1   = (const float*)d_in[7];   // (512)
  const float* cpb_w2   = (const float*)d_in[8];   // (16,512)
  const float* rel_tab  = (const float*)d_in[9];   // (1,23,23,2) = 529x2
  const int*   rel_idx  = (const int*)d_in[10];    // (144,144)
  float* out = (float*)d_out;

  char* ws = (char*)d_ws;
  unsigned short* x_bf    = (unsigned short*)(ws);                 // 37,748,736 B
  unsigned short* wq_bf   = (unsigned short*)(ws + 37748736);      //  1,572,864 B
  unsigned short* wp_bf   = (unsigned short*)(ws + 39321600);      //    524,288 B
  unsigned short* qkv_ws  = (unsigned short*)(ws + 39845888);      // 113,246,208 B
  unsigned short* attn_ws = (unsigned short*)(ws + 153092096);     // 37,748,736 B
  float*          tbl_ws  = (float*)(ws + 190840832);              //     33,856 B
  unsigned short* maskbf  = (unsigned short*)(ws + 190874688);     //  2,654,208 B
  unsigned short* biasbf  = (unsigned short*)(ws + 193528896);     //    663,552 B
  // total 194,192,448 B

  // fp32 -> bf16 conversions
  cvt_f32_bf16<<<2048, 256, 0, stream>>>((const float4*)x, x_bf, 4718592);
  cvt_f32_bf16<<<768, 256, 0, stream>>>((const float4*)qkv_w, wq_bf, 196608);
  cvt_f32_bf16<<<256, 256, 0, stream>>>((const float4*)proj_w, wp_bf, 65536);
  cvt_f32_bf16<<<1296, 256, 0, stream>>>((const float4*)mask, maskbf, 331776);

  // CPB bias (bf16 table)
  cpb_mlp<<<529, 512, 0, stream>>>(rel_tab, cpb_w1, cpb_b1, cpb_w2, tbl_ws);
  bias_gather<<<1296, 256, 0, stream>>>(tbl_ws, rel_idx, biasbf);

  // QKV GEMM: (36864,512) x (1536,512)^T -> bf16 (36864,1536), q cols scaled
  gemm_bt_k<true, true><<<dim3(12, 288), 256, 0, stream>>>(
      x_bf, wq_bf, qkv_b, (void*)qkv_ws, 1536, 512);

  // attention: one block per (head, window-batch)
  attn_k<<<dim3(16, 256), 256, 0, stream>>>(qkv_ws, maskbf, biasbf, attn_ws);

  // proj GEMM: (36864,512) x (512,512)^T -> f32 out
  gemm_bt_k<false, false><<<dim3(4, 288), 256, 0, stream>>>(
      attn_ws, wp_bf, proj_b, (void*)out, 512, 512);
}

// Round 4
// 404.966 us; speedup vs baseline: 1.0717x; 1.0065x over previous
//
#include <hip/hip_runtime.h>

// ---------------------------------------------------------------------------
// SwinV2 WindowAttention fused pipeline (bf16 MFMA, fp32 accumulate)
//   Bw=256 windows, N=144 tokens, C=512, H=16 heads, hd=32, nW=64
// Pipeline: cvt(x,Wqkv,Wproj,mask) -> cpb-mlp -> bias gather(bf16) ->
//           GEMM qkv (bf16 out, q pre-scaled) -> attn (swapped-QK^T,
//           in-register softmax, batched fragment preload) -> GEMM proj
// ---------------------------------------------------------------------------

using f32x4  = __attribute__((ext_vector_type(4))) float;
using bf16x8 = __attribute__((ext_vector_type(8))) short;

__device__ __forceinline__ unsigned short f2bf(float f) {
  unsigned u = __float_as_uint(f);
  u = (u + 0x7fffu + ((u >> 16) & 1u)) >> 16;   // RNE
  return (unsigned short)u;
}
__device__ __forceinline__ float bf2f(unsigned short s) {
  return __uint_as_float(((unsigned)s) << 16);
}

typedef __attribute__((address_space(1))) unsigned int as1_u32;
typedef __attribute__((address_space(3))) unsigned int as3_u32;

__device__ __forceinline__ void gll16(const void* g, void* l) {
  // async global->LDS, 16B per lane; LDS dest must be wave-uniform base.
  __builtin_amdgcn_global_load_lds((const as1_u32*)g, (as3_u32*)l, 16, 0, 0);
}

// --------------------------- fp32 -> bf16 convert ---------------------------
__global__ void cvt_f32_bf16(const float4* __restrict__ in,
                             unsigned short* __restrict__ out, int n4) {
  int i = blockIdx.x * blockDim.x + threadIdx.x;
  int stride = gridDim.x * blockDim.x;
  for (; i < n4; i += stride) {
    float4 v = in[i];
    ushort4 o;
    o.x = f2bf(v.x); o.y = f2bf(v.y); o.z = f2bf(v.z); o.w = f2bf(v.w);
    *(ushort4*)(out + (size_t)i * 4) = o;
  }
}

// --------------------------- CPB MLP: tbl(529,16) ---------------------------
__global__ void cpb_mlp(const float* __restrict__ tbl_in,  // (529,2)
                        const float* __restrict__ w1,      // (512,2)
                        const float* __restrict__ b1,      // (512)
                        const float* __restrict__ w2,      // (16,512)
                        float* __restrict__ tbl_out) {     // (529,16)
  __shared__ float hid[512];
  const int p = blockIdx.x;
  const int t = threadIdx.x;
  float t0 = tbl_in[p * 2 + 0], t1 = tbl_in[p * 2 + 1];
  float hv = fmaf(w1[t * 2 + 0], t0, fmaf(w1[t * 2 + 1], t1, b1[t]));
  hid[t] = fmaxf(hv, 0.f);
  __syncthreads();
  const int head = t >> 5, j = t & 31;
  float partial = 0.f;
  for (int i = j; i < 512; i += 32) partial += hid[i] * w2[head * 512 + i];
#pragma unroll
  for (int mk = 16; mk >= 1; mk >>= 1) partial += __shfl_xor(partial, mk, 32);
  if (j == 0) tbl_out[p * 16 + head] = partial;
}

// ---------------- gather: bias_bf[h][n][m] (16,144,144) bf16 ----------------
__global__ void bias_gather(const float* __restrict__ tbl,          // (529,16)
                            const int* __restrict__ idx,            // (144,144)
                            unsigned short* __restrict__ bias_bf) { // (16,20736)
  int f = blockIdx.x * 256 + threadIdx.x;
  if (f >= 16 * 20736) return;
  int h = f / 20736;
  int p = f - h * 20736;
  bias_bf[f] = f2bf(tbl[idx[p] * 16 + h]);
}

// --------------------------- bf16 GEMM, C = A * B^T -------------------------
// A: [M][K] bf16 row-major, B: [N][K] bf16 row-major, K multiple of 32.
// 128x128 tile, 4 waves each owning 4x4 16x16 sub-tiles. m97 structure.
// QSCALE: multiply output cols < 512 by hd^-0.5 (folds attn scale into q).
template <bool OUT_BF16, bool QSCALE>
__global__ __launch_bounds__(256) void gemm_bt_k(
    const unsigned short* __restrict__ A, const unsigned short* __restrict__ B,
    const float* __restrict__ bias, void* __restrict__ C, int N, int K) {
  __shared__ __align__(16) unsigned short As[128 * 32];
  __shared__ __align__(16) unsigned short Bs[128 * 32];
  const int tid = threadIdx.x;
  const int wave = tid >> 6, lane = tid & 63;
  const int m0 = blockIdx.y << 7, n0 = blockIdx.x << 7;
  const int wr = wave >> 1, wc = wave & 1;
  const int l15 = lane & 15, l4 = lane >> 4;

  f32x4 acc[4][4] = {};

  const unsigned short* gA = A + (size_t)(m0 + wave * 32 + (lane >> 2)) * K + (lane & 3) * 8;
  const unsigned short* gB = B + (size_t)(n0 + wave * 32 + (lane >> 2)) * K + (lane & 3) * 8;
  unsigned short* lA = As + wave * 32 * 32;  // wave-uniform LDS base
  unsigned short* lB = Bs + wave * 32 * 32;

  for (int k0 = 0; k0 < K; k0 += 32) {
    __syncthreads();
    gll16(gA + k0, lA);
    gll16(gA + k0 + (size_t)16 * K, lA + 16 * 32);
    gll16(gB + k0, lB);
    gll16(gB + k0 + (size_t)16 * K, lB + 16 * 32);
    __syncthreads();
    bf16x8 af[4], bfr[4];
#pragma unroll
    for (int t = 0; t < 4; ++t) {
      af[t]  = *(const bf16x8*)(As + (wr * 64 + t * 16 + l15) * 32 + l4 * 8);
      bfr[t] = *(const bf16x8*)(Bs + (wc * 64 + t * 16 + l15) * 32 + l4 * 8);
    }
#pragma unroll
    for (int i = 0; i < 4; ++i)
#pragma unroll
      for (int j = 0; j < 4; ++j)
        acc[i][j] = __builtin_amdgcn_mfma_f32_16x16x32_bf16(af[i], bfr[j], acc[i][j], 0, 0, 0);
  }

#pragma unroll
  for (int i = 0; i < 4; ++i) {
    int rowb = m0 + wr * 64 + i * 16 + l4 * 4;
#pragma unroll
    for (int j = 0; j < 4; ++j) {
      int col = n0 + wc * 64 + j * 16 + l15;
      float bv = bias[col];
#pragma unroll
      for (int r = 0; r < 4; ++r) {
        size_t off = (size_t)(rowb + r) * N + col;
        float v = acc[i][j][r] + bv;
        if (QSCALE && col < 512) v *= 0.17677669529663688f;  // hd^-0.5
        if (OUT_BF16) ((unsigned short*)C)[off] = f2bf(v);
        else          ((float*)C)[off] = v;
      }
    }
  }
}

// ------------------------------- attention ----------------------------------
// One block (256 thr, 4 waves) per (b, h). qkv: [36864][1536] bf16
// (cols 0-511 = q (pre-scaled), 512-1023 = k, 1024-1535 = v at h*32+d).
// Swapped QK^T: mfma(K,Q) = S^T so lane holds row n = rt*16+l15, keys
// m = kt*16+l4*4+r -> softmax fully in-register (2 shfl_xor).
// S^T phase batches ALL 9 K-fragment + mask + bias loads into registers
// before the MFMA cluster (one latency wait instead of nine).
// LDS: P[144][152] + Vt[32][152] = 53,504 B -> 3 blocks/CU.
__global__ __launch_bounds__(256, 4) void attn_k(
    const unsigned short* __restrict__ qkv,
    const unsigned short* __restrict__ maskbf,   // (64,144,144) bf16
    const unsigned short* __restrict__ biasbf,   // (16,144,144) bf16
    unsigned short* __restrict__ aout) {
  __shared__ __align__(16) unsigned short P[144 * 152];
  __shared__ __align__(16) unsigned short Vt[32 * 152];

  const int h = blockIdx.x, b = blockIdx.y;
  const int tid = threadIdx.x;
  const int wave = tid >> 6, lane = tid & 63;
  const int l15 = lane & 15, l4 = lane >> 4;
  const size_t base = (size_t)b * 144 * 1536;

  // ---- stage V transposed. chunk = dblk*144 + m so consecutive lanes hit
  //      consecutive m -> Vt write banks spread (2-way max, free).
  for (int c = tid; c < 576; c += 256) {
    int dblk = c / 144;
    int m = c - dblk * 144;
    uint4 v = *(const uint4*)(qkv + base + (size_t)m * 1536 + 1024 + h * 32 + dblk * 8);
    unsigned short tmp[8];
    *(uint4*)tmp = v;
#pragma unroll
    for (int j = 0; j < 8; ++j) Vt[(dblk * 8 + j) * 152 + m] = tmp[j];
  }

  // ---- S^T + in-register softmax + P write, per row-tile
  const unsigned short* mrow = maskbf + (size_t)(b & 63) * 20736;
  const unsigned short* brow = biasbf + (size_t)h * 20736;
  for (int rt = wave; rt < 9; rt += 4) {
    const int n = rt * 16 + l15;
    // B-frag: Q[n][k=l4*8+j] (q pre-scaled by hd^-0.5 in GEMM epilogue)
    bf16x8 qf = *(const bf16x8*)(qkv + base + (size_t)n * 1536 + h * 32 + l4 * 8);
    // ---- phase 1: issue ALL loads (independent), fold mask+bias into acc
    bf16x8 kf[9];
#pragma unroll
    for (int kt = 0; kt < 9; ++kt)
      kf[kt] = *(const bf16x8*)(qkv + base + (size_t)(kt * 16 + l15) * 1536 + 512 + h * 32 + l4 * 8);
    f32x4 acc[9];
#pragma unroll
    for (int kt = 0; kt < 9; ++kt) {
      const int mq = kt * 16 + l4 * 4;   // lane's 4 consecutive m values
      ushort4 mv = *(const ushort4*)(mrow + n * 144 + mq);
      ushort4 bv = *(const ushort4*)(brow + n * 144 + mq);
      f32x4 ci;
      ci[0] = bf2f(mv.x) + bf2f(bv.x);
      ci[1] = bf2f(mv.y) + bf2f(bv.y);
      ci[2] = bf2f(mv.z) + bf2f(bv.z);
      ci[3] = bf2f(mv.w) + bf2f(bv.w);
      acc[kt] = ci;
    }
    // ---- phase 2: 9 MFMAs (D = K * Q^T = S^T)
#pragma unroll
    for (int kt = 0; kt < 9; ++kt)
      acc[kt] = __builtin_amdgcn_mfma_f32_16x16x32_bf16(kf[kt], qf, acc[kt], 0, 0, 0);
    // softmax over the 144 keys of row n: 36 in-lane + lanes 16/32
    float mx = -3.0e38f;
#pragma unroll
    for (int kt = 0; kt < 9; ++kt)
#pragma unroll
      for (int r = 0; r < 4; ++r) mx = fmaxf(mx, acc[kt][r]);
    mx = fmaxf(mx, __shfl_xor(mx, 16));
    mx = fmaxf(mx, __shfl_xor(mx, 32));
    float sum = 0.f;
#pragma unroll
    for (int kt = 0; kt < 9; ++kt)
#pragma unroll
      for (int r = 0; r < 4; ++r) {
        float p = __expf(acc[kt][r] - mx);
        acc[kt][r] = p;
        sum += p;
      }
    sum += __shfl_xor(sum, 16);
    sum += __shfl_xor(sum, 32);
    float inv = 1.0f / sum;
    unsigned short* prow = P + n * 152;
#pragma unroll
    for (int kt = 0; kt < 9; ++kt) {
      ushort4 o;
      o.x = f2bf(acc[kt][0] * inv);
      o.y = f2bf(acc[kt][1] * inv);
      o.z = f2bf(acc[kt][2] * inv);
      o.w = f2bf(acc[kt][3] * inv);
      *(ushort4*)(prow + kt * 16 + l4 * 4) = o;   // b64 write, 2-way banks
    }
  }
  __syncthreads();

  // ---- O = P V : 18 tiles (9 row-tiles x 2 d-tiles), exact K=144
  for (int tt = wave; tt < 18; tt += 4) {
    int rt = tt >> 1, dj = tt & 1;
    f32x4 c = {0.f, 0.f, 0.f, 0.f};
    const unsigned short* pa = P + (rt * 16 + l15) * 152;
    const unsigned short* vb = Vt + (dj * 16 + l15) * 152;
#pragma unroll
    for (int ks = 0; ks < 4; ++ks) {
      bf16x8 ap = *(const bf16x8*)(pa + ks * 32 + l4 * 8);
      bf16x8 bv = *(const bf16x8*)(vb + ks * 32 + l4 * 8);
      c = __builtin_amdgcn_mfma_f32_16x16x32_bf16(ap, bv, c, 0, 0, 0);
    }
    {
      bf16x8 ap = {}, bv = {};
      if (l4 < 2) {
        ap = *(const bf16x8*)(pa + 128 + l4 * 8);
        bv = *(const bf16x8*)(vb + 128 + l4 * 8);
      }
      c = __builtin_amdgcn_mfma_f32_16x16x32_bf16(ap, bv, c, 0, 0, 0);
    }
#pragma unroll
    for (int r = 0; r < 4; ++r) {
      int n = rt * 16 + l4 * 4 + r;
      int d = dj * 16 + l15;
      aout[((size_t)(b * 144 + n)) * 512 + h * 32 + d] = f2bf(c[r]);
    }
  }
}

// ------------------------------- launcher -----------------------------------
extern "C" void kernel_launch(void* const* d_in, const int* in_sizes, int n_in,
                              void* d_out, int out_size, void* d_ws, size_t ws_size,
                              hipStream_t stream) {
  const float* x        = (const float*)d_in[0];   // (256,144,512)
  const float* mask     = (const float*)d_in[1];   // (64,144,144)
  const float* qkv_w    = (const float*)d_in[2];   // (1536,512)
  const float* qkv_b    = (const float*)d_in[3];   // (1536)
  const float* proj_w   = (const float*)d_in[4];   // (512,512)
  const float* proj_b   = (const float*)d_in[5];   // (512)
  const float* cpb_w1   = (const float*)d_in[6];   // (512,2)
  const float* cpb_b1   = (const float*)d_in[7];   // (512)
  const float* cpb_w2   = (const float*)d_in[8];   // (16,512)
  const float* rel_tab  = (const float*)d_in[9];   // (1,23,23,2) = 529x2
  const int*   rel_idx  = (const int*)d_in[10];    // (144,144)
  float* out = (float*)d_out;

  char* ws = (char*)d_ws;
  unsigned short* x_bf    = (unsigned short*)(ws);                 // 37,748,736 B
  unsigned short* wq_bf   = (unsigned short*)(ws + 37748736);      //  1,572,864 B
  unsigned short* wp_bf   = (unsigned short*)(ws + 39321600);      //    524,288 B
  unsigned short* qkv_ws  = (unsigned short*)(ws + 39845888);      // 113,246,208 B
  unsigned short* attn_ws = (unsigned short*)(ws + 153092096);     // 37,748,736 B
  float*          tbl_ws  = (float*)(ws + 190840832);              //     33,856 B
  unsigned short* maskbf  = (unsigned short*)(ws + 190874688);     //  2,654,208 B
  unsigned short* biasbf  = (unsigned short*)(ws + 193528896);     //    663,552 B
  // total 194,192,448 B

  // fp32 -> bf16 conversions
  cvt_f32_bf16<<<2048, 256, 0, stream>>>((const float4*)x, x_bf, 4718592);
  cvt_f32_bf16<<<768, 256, 0, stream>>>((const float4*)qkv_w, wq_bf, 196608);
  cvt_f32_bf16<<<256, 256, 0, stream>>>((const float4*)proj_w, wp_bf, 65536);
  cvt_f32_bf16<<<1296, 256, 0, stream>>>((const float4*)mask, maskbf, 331776);

  // CPB bias (bf16 table)
  cpb_mlp<<<529, 512, 0, stream>>>(rel_tab, cpb_w1, cpb_b1, cpb_w2, tbl_ws);
  bias_gather<<<1296, 256, 0, stream>>>(tbl_ws, rel_idx, biasbf);

  // QKV GEMM: (36864,512) x (1536,512)^T -> bf16 (36864,1536), q cols scaled
  gemm_bt_k<true, true><<<dim3(12, 288), 256, 0, stream>>>(
      x_bf, wq_bf, qkv_b, (void*)qkv_ws, 1536, 512);

  // attention: one block per (head, window-batch)
  attn_k<<<dim3(16, 256), 256, 0, stream>>>(qkv_ws, maskbf, biasbf, attn_ws);

  // proj GEMM: (36864,512) x (512,512)^T -> f32 out
  gemm_bt_k<false, false><<<dim3(4, 288), 256, 0, stream>>>(
      attn_ws, wp_bf, proj_b, (void*)out, 512, 512);
}

// Round 5
// 374.390 us; speedup vs baseline: 1.1592x; 1.0817x over previous
//
#include <hip/hip_runtime.h>

// ---------------------------------------------------------------------------
// SwinV2 WindowAttention fused pipeline (bf16 MFMA, fp32 accumulate)
//   Bw=256 windows, N=144 tokens, C=512, H=16 heads, hd=32, nW=64
// Pipeline: cvt(x,Wqkv,Wproj) -> cpb-mlp -> bias gather(f32*log2e) ->
//           GEMM qkv (bf16 out, q pre-scaled by hd^-0.5*log2e) ->
//           attn (K in LDS, swapped-QK^T, exp2 softmax, deferred norm) ->
//           GEMM proj (f32 out)
// ---------------------------------------------------------------------------

using f32x4  = __attribute__((ext_vector_type(4))) float;
using bf16x8 = __attribute__((ext_vector_type(8))) short;

#define LOG2E 1.4426950408889634f

#if __has_builtin(__builtin_amdgcn_exp2f)
#define EXP2(x) __builtin_amdgcn_exp2f(x)
#else
#define EXP2(x) __expf((x) * 0.6931471805599453f)
#endif
#if __has_builtin(__builtin_amdgcn_rcpf)
#define RCP(x) __builtin_amdgcn_rcpf(x)
#else
#define RCP(x) (1.0f / (x))
#endif

__device__ __forceinline__ unsigned short f2bf(float f) {
  unsigned u = __float_as_uint(f);
  u = (u + 0x7fffu + ((u >> 16) & 1u)) >> 16;   // RNE
  return (unsigned short)u;
}

// pack 2 f32 -> 2 bf16 (RNE) in one instruction
__device__ __forceinline__ unsigned cvt_pk_bf16(float lo, float hi) {
  unsigned r;
  asm("v_cvt_pk_bf16_f32 %0, %1, %2" : "=v"(r) : "v"(lo), "v"(hi));
  return r;
}

typedef __attribute__((address_space(1))) unsigned int as1_u32;
typedef __attribute__((address_space(3))) unsigned int as3_u32;

__device__ __forceinline__ void gll16(const void* g, void* l) {
  // async global->LDS, 16B per lane; LDS dest must be wave-uniform base.
  __builtin_amdgcn_global_load_lds((const as1_u32*)g, (as3_u32*)l, 16, 0, 0);
}

// --------------------------- fp32 -> bf16 convert ---------------------------
__global__ void cvt_f32_bf16(const float4* __restrict__ in,
                             unsigned short* __restrict__ out, int n4) {
  int i = blockIdx.x * blockDim.x + threadIdx.x;
  int stride = gridDim.x * blockDim.x;
  for (; i < n4; i += stride) {
    float4 v = in[i];
    ushort4 o;
    o.x = f2bf(v.x); o.y = f2bf(v.y); o.z = f2bf(v.z); o.w = f2bf(v.w);
    *(ushort4*)(out + (size_t)i * 4) = o;
  }
}

// --------------------------- CPB MLP: tbl(529,16) ---------------------------
__global__ void cpb_mlp(const float* __restrict__ tbl_in,  // (529,2)
                        const float* __restrict__ w1,      // (512,2)
                        const float* __restrict__ b1,      // (512)
                        const float* __restrict__ w2,      // (16,512)
                        float* __restrict__ tbl_out) {     // (529,16)
  __shared__ float hid[512];
  const int p = blockIdx.x;
  const int t = threadIdx.x;
  float t0 = tbl_in[p * 2 + 0], t1 = tbl_in[p * 2 + 1];
  float hv = fmaf(w1[t * 2 + 0], t0, fmaf(w1[t * 2 + 1], t1, b1[t]));
  hid[t] = fmaxf(hv, 0.f);
  __syncthreads();
  const int head = t >> 5, j = t & 31;
  float partial = 0.f;
  for (int i = j; i < 512; i += 32) partial += hid[i] * w2[head * 512 + i];
#pragma unroll
  for (int mk = 16; mk >= 1; mk >>= 1) partial += __shfl_xor(partial, mk, 32);
  if (j == 0) tbl_out[p * 16 + head] = partial;
}

// ------- gather: bias_f[h][n][m] (16,144,144) f32, pre-scaled by log2e ------
__global__ void bias_gather(const float* __restrict__ tbl,      // (529,16)
                            const int* __restrict__ idx,        // (144,144)
                            float* __restrict__ bias_f) {       // (16,20736)
  int f = blockIdx.x * 256 + threadIdx.x;
  if (f >= 16 * 20736) return;
  int h = f / 20736;
  int p = f - h * 20736;
  bias_f[f] = tbl[idx[p] * 16 + h] * LOG2E;
}

// --------------------------- bf16 GEMM, C = A * B^T -------------------------
// A: [M][K] bf16 row-major, B: [N][K] bf16 row-major, K multiple of 32.
// 128x128 tile, 4 waves each owning 4x4 16x16 sub-tiles. m97 structure.
// QSCALE: multiply output cols < 512 by hd^-0.5 * log2e (attn exp2 fold).
template <bool OUT_BF16, bool QSCALE>
__global__ __launch_bounds__(256) void gemm_bt_k(
    const unsigned short* __restrict__ A, const unsigned short* __restrict__ B,
    const float* __restrict__ bias, void* __restrict__ C, int N, int K) {
  __shared__ __align__(16) unsigned short As[128 * 32];
  __shared__ __align__(16) unsigned short Bs[128 * 32];
  const int tid = threadIdx.x;
  const int wave = tid >> 6, lane = tid & 63;
  const int m0 = blockIdx.y << 7, n0 = blockIdx.x << 7;
  const int wr = wave >> 1, wc = wave & 1;
  const int l15 = lane & 15, l4 = lane >> 4;

  f32x4 acc[4][4] = {};

  const unsigned short* gA = A + (size_t)(m0 + wave * 32 + (lane >> 2)) * K + (lane & 3) * 8;
  const unsigned short* gB = B + (size_t)(n0 + wave * 32 + (lane >> 2)) * K + (lane & 3) * 8;
  unsigned short* lA = As + wave * 32 * 32;  // wave-uniform LDS base
  unsigned short* lB = Bs + wave * 32 * 32;

  for (int k0 = 0; k0 < K; k0 += 32) {
    __syncthreads();
    gll16(gA + k0, lA);
    gll16(gA + k0 + (size_t)16 * K, lA + 16 * 32);
    gll16(gB + k0, lB);
    gll16(gB + k0 + (size_t)16 * K, lB + 16 * 32);
    __syncthreads();
    bf16x8 af[4], bfr[4];
#pragma unroll
    for (int t = 0; t < 4; ++t) {
      af[t]  = *(const bf16x8*)(As + (wr * 64 + t * 16 + l15) * 32 + l4 * 8);
      bfr[t] = *(const bf16x8*)(Bs + (wc * 64 + t * 16 + l15) * 32 + l4 * 8);
    }
#pragma unroll
    for (int i = 0; i < 4; ++i)
#pragma unroll
      for (int j = 0; j < 4; ++j)
        acc[i][j] = __builtin_amdgcn_mfma_f32_16x16x32_bf16(af[i], bfr[j], acc[i][j], 0, 0, 0);
  }

#pragma unroll
  for (int i = 0; i < 4; ++i) {
    int rowb = m0 + wr * 64 + i * 16 + l4 * 4;
#pragma unroll
    for (int j = 0; j < 4; ++j) {
      int col = n0 + wc * 64 + j * 16 + l15;
      float bv = bias[col];
#pragma unroll
      for (int r = 0; r < 4; ++r) {
        size_t off = (size_t)(rowb + r) * N + col;
        float v = acc[i][j][r] + bv;
        if (QSCALE && col < 512) v *= 0.17677669529663688f * LOG2E;
        if (OUT_BF16) ((unsigned short*)C)[off] = f2bf(v);
        else          ((float*)C)[off] = v;
      }
    }
  }
}

// ------------------------------- attention ----------------------------------
// One block (256 thr, 4 waves) per (b, h); 1-D grid XCD-swizzled so all 16 h
// of a window run consecutively on one XCD (qkv/mask L2 locality).
// qkv: [36864][1536] bf16 (q cols pre-scaled by hd^-0.5*log2e, k at +512,
// v at +1024). K staged once per block in LDS (swizzled source, linear LDS).
// Swapped QK^T: mfma(K,Q)=S^T -> lane holds row n=rt*16+l15, m=kt*16+l4*4+r.
// Softmax: exp2, no max-sub (args in [-145,~4]), deferred 1/sum (invs[]).
// LDS: Ks(9216, overlaid by Vt) + invs(576) + P[144][152](43776) = 53,568 B.
__global__ __launch_bounds__(256, 3) void attn_k(
    const unsigned short* __restrict__ qkv,
    const float* __restrict__ maskf,   // (64,144,144) f32 (raw input)
    const float* __restrict__ biasf,   // (16,144,144) f32, pre-scaled log2e
    unsigned short* __restrict__ aout) {
  __shared__ __align__(16) char smem[53568];
  unsigned short* Ks  = (unsigned short*)smem;            // 9,216 B
  unsigned short* Vt  = (unsigned short*)smem;            // overlay after S^T
  float*          invs = (float*)(smem + 9216);           // 576 B
  unsigned short* P   = (unsigned short*)(smem + 9792);   // 43,776 B

  // XCD swizzle: all 16 heads of a window consecutive on one XCD
  const int lid = blockIdx.x;
  const int xc = lid & 7, slot = lid >> 3;
  const int b = (xc << 5) + (slot >> 4);
  const int h = slot & 15;

  const int tid = threadIdx.x;
  const int wave = tid >> 6, lane = tid & 63;
  const int l15 = lane & 15, l4 = lane >> 4;
  const size_t base = (size_t)b * 144 * 1536;

  // ---- stage K into LDS (async). Natural chunk i = r*4+half (16B units);
  //      stored slot s = r*4 + (half ^ ((r>>1)&3))  -> 2-way banks on read.
  for (int c = wave; c < 9; c += 4) {
    int s = c * 64 + lane;
    int r = s >> 2;
    int halfd = (s & 3) ^ ((r >> 1) & 3);
    gll16(qkv + base + (size_t)r * 1536 + 512 + h * 32 + halfd * 8,
          Ks + c * 512);
  }
  __syncthreads();

  // ---- S^T + in-register softmax + P write, per row-tile
  const float* mrow = maskf + (size_t)(b & 63) * 20736;
  const float* brow = biasf + (size_t)h * 20736;
  for (int rt = wave; rt < 9; rt += 4) {
    const int n = rt * 16 + l15;
    // B-frag: Q[n][k=l4*8+j] (pre-scaled)
    bf16x8 qf = *(const bf16x8*)(qkv + base + (size_t)n * 1536 + h * 32 + l4 * 8);
    f32x4 acc[9];
#pragma unroll
    for (int kt = 0; kt < 9; ++kt) {
      const int mq = kt * 16 + l4 * 4;   // lane's 4 consecutive m values
      float4 mv = *(const float4*)(mrow + n * 144 + mq);
      float4 bv = *(const float4*)(brow + n * 144 + mq);
      f32x4 ci;
      ci[0] = fmaf(mv.x, LOG2E, bv.x);
      ci[1] = fmaf(mv.y, LOG2E, bv.y);
      ci[2] = fmaf(mv.z, LOG2E, bv.z);
      ci[3] = fmaf(mv.w, LOG2E, bv.w);
      // A-frag from LDS (swizzled slot)
      int r = kt * 16 + l15;
      bf16x8 kf = *(const bf16x8*)(Ks + (((r << 2) + (l4 ^ ((r >> 1) & 3))) << 3));
      acc[kt] = __builtin_amdgcn_mfma_f32_16x16x32_bf16(kf, qf, ci, 0, 0, 0);
    }
    // softmax (base-2, no max-subtraction; masked -> exp2(~-145) = 0)
    float sum = 0.f;
#pragma unroll
    for (int kt = 0; kt < 9; ++kt)
#pragma unroll
      for (int r = 0; r < 4; ++r) {
        float p = EXP2(acc[kt][r]);
        acc[kt][r] = p;
        sum += p;
      }
    sum += __shfl_xor(sum, 16);
    sum += __shfl_xor(sum, 32);
    if (l4 == 0) invs[n] = RCP(sum);
    // pack unnormalized P (values <= ~16, bf16-safe)
    unsigned short* prow = P + n * 152;
#pragma unroll
    for (int kt = 0; kt < 9; ++kt) {
      uint2 w;
      w.x = cvt_pk_bf16(acc[kt][0], acc[kt][1]);
      w.y = cvt_pk_bf16(acc[kt][2], acc[kt][3]);
      *(uint2*)(prow + kt * 16 + l4 * 4) = w;
    }
  }
  __syncthreads();   // Ks dead; P/invs complete

  // ---- stage V transposed over Ks region. Vt[32][144] (no pad; 4-way on
  //      read = 1.58x, acceptable). Consecutive lanes -> consecutive m.
  for (int c = tid; c < 576; c += 256) {
    int dblk = c / 144;
    int m = c - dblk * 144;
    uint4 v = *(const uint4*)(qkv + base + (size_t)m * 1536 + 1024 + h * 32 + dblk * 8);
    unsigned short tmp[8];
    *(uint4*)tmp = v;
#pragma unroll
    for (int j = 0; j < 8; ++j) Vt[(dblk * 8 + j) * 144 + m] = tmp[j];
  }
  __syncthreads();

  // ---- O = P V * inv : 18 tiles (9 row-tiles x 2 d-tiles), exact K=144
  for (int tt = wave; tt < 18; tt += 4) {
    int rt = tt >> 1, dj = tt & 1;
    f32x4 c = {0.f, 0.f, 0.f, 0.f};
    const unsigned short* pa = P + (rt * 16 + l15) * 152;
    const unsigned short* vb = Vt + (dj * 16 + l15) * 144;
#pragma unroll
    for (int ks = 0; ks < 4; ++ks) {
      bf16x8 ap = *(const bf16x8*)(pa + ks * 32 + l4 * 8);
      bf16x8 bv = *(const bf16x8*)(vb + ks * 32 + l4 * 8);
      c = __builtin_amdgcn_mfma_f32_16x16x32_bf16(ap, bv, c, 0, 0, 0);
    }
    {
      bf16x8 ap = {}, bv = {};
      if (l4 < 2) {
        ap = *(const bf16x8*)(pa + 128 + l4 * 8);
        bv = *(const bf16x8*)(vb + 128 + l4 * 8);
      }
      c = __builtin_amdgcn_mfma_f32_16x16x32_bf16(ap, bv, c, 0, 0, 0);
    }
#pragma unroll
    for (int r = 0; r < 4; ++r) {
      int n = rt * 16 + l4 * 4 + r;
      int d = dj * 16 + l15;
      float iv = invs[n];   // broadcast within lane groups
      aout[((size_t)(b * 144 + n)) * 512 + h * 32 + d] = f2bf(c[r] * iv);
    }
  }
}

// ------------------------------- launcher -----------------------------------
extern "C" void kernel_launch(void* const* d_in, const int* in_sizes, int n_in,
                              void* d_out, int out_size, void* d_ws, size_t ws_size,
                              hipStream_t stream) {
  const float* x        = (const float*)d_in[0];   // (256,144,512)
  const float* mask     = (const float*)d_in[1];   // (64,144,144)
  const float* qkv_w    = (const float*)d_in[2];   // (1536,512)
  const float* qkv_b    = (const float*)d_in[3];   // (1536)
  const float* proj_w   = (const float*)d_in[4];   // (512,512)
  const float* proj_b   = (const float*)d_in[5];   // (512)
  const float* cpb_w1   = (const float*)d_in[6];   // (512,2)
  const float* cpb_b1   = (const float*)d_in[7];   // (512)
  const float* cpb_w2   = (const float*)d_in[8];   // (16,512)
  const float* rel_tab  = (const float*)d_in[9];   // (1,23,23,2) = 529x2
  const int*   rel_idx  = (const int*)d_in[10];    // (144,144)
  float* out = (float*)d_out;

  char* ws = (char*)d_ws;
  unsigned short* x_bf    = (unsigned short*)(ws);                 // 37,748,736 B
  unsigned short* wq_bf   = (unsigned short*)(ws + 37748736);      //  1,572,864 B
  unsigned short* wp_bf   = (unsigned short*)(ws + 39321600);      //    524,288 B
  unsigned short* qkv_ws  = (unsigned short*)(ws + 39845888);      // 113,246,208 B
  unsigned short* attn_ws = (unsigned short*)(ws + 153092096);     // 37,748,736 B
  float*          tbl_ws  = (float*)(ws + 190840832);              //     33,856 B
  float*          biasf   = (float*)(ws + 190874688);              //  1,327,104 B
  // total 192,201,792 B

  // fp32 -> bf16 conversions
  cvt_f32_bf16<<<2048, 256, 0, stream>>>((const float4*)x, x_bf, 4718592);
  cvt_f32_bf16<<<768, 256, 0, stream>>>((const float4*)qkv_w, wq_bf, 196608);
  cvt_f32_bf16<<<256, 256, 0, stream>>>((const float4*)proj_w, wp_bf, 65536);

  // CPB bias (f32 table, pre-scaled by log2e)
  cpb_mlp<<<529, 512, 0, stream>>>(rel_tab, cpb_w1, cpb_b1, cpb_w2, tbl_ws);
  bias_gather<<<1296, 256, 0, stream>>>(tbl_ws, rel_idx, biasf);

  // QKV GEMM: (36864,512) x (1536,512)^T -> bf16 (36864,1536), q pre-scaled
  gemm_bt_k<true, true><<<dim3(12, 288), 256, 0, stream>>>(
      x_bf, wq_bf, qkv_b, (void*)qkv_ws, 1536, 512);

  // attention: 4096 blocks, XCD-swizzled (b,h) mapping inside kernel
  attn_k<<<4096, 256, 0, stream>>>(qkv_ws, mask, biasf, attn_ws);

  // proj GEMM: (36864,512) x (512,512)^T -> f32 out
  gemm_bt_k<false, false><<<dim3(4, 288), 256, 0, stream>>>(
      attn_ws, wp_bf, proj_b, (void*)out, 512, 512);
}